// Round 3
// baseline (163.242 us; speedup 1.0000x reference)
//
#include <hip/hip_runtime.h>
#include <hip/hip_bf16.h>
#include <math.h>

#define N_NODES 50000
#define N_EDGES 800000
#define IN_DIM  128
#define HID_DIM 64

#define NBKT     196        // buckets of 256 nodes: bucket = node >> 8
#define BKT_CAP  5000       // mean 4092, sd 64 -> +14 sigma, safe
#define NPASSC   200        // partition blocks, 4000 edges each
#define EDGES_PER_PASSC (N_EDGES / NPASSC)   // 4000
#define NGEMM    3125       // 50000 / 16 nodes per block

// =============== kernel 1: fused bucket-partition (blocks 0..199) =============
// =============== + gemm h1b = bf16(x @ W1) (blocks 200..3324) =================
// gemm v3: register-W + uniform-x. W column slice lives in 32 VGPRs per thread
// (K split across the 4 waves); x is read with wave-uniform addresses (scalar
// cache path) so the inner loop issues NO per-iteration LDS reads. Cross-wave
// K-partials reduced through a 16KB psum overlaid on w1s.
__global__ __launch_bounds__(256)
void partgemm_kernel(const int* __restrict__ src, const int* __restrict__ dst,
                     const float* __restrict__ ew, int* __restrict__ gcursor,
                     int2* __restrict__ edge_b,
                     const float* __restrict__ x, const float* __restrict__ W1,
                     __hip_bfloat16* __restrict__ h1b) {
    __shared__ float w1s[IN_DIM * HID_DIM];  // 32 KB (PassC overlays counters; gemm overlays psum)
    int bid = blockIdx.x;
    int tid = threadIdx.x;
    if (bid < NPASSC) {
        // ---- PassC: partition into buckets ----
        int* cnt1    = (int*)w1s;            // [196]
        int* cnt2    = cnt1 + NBKT;          // [196]
        int* runbase = cnt2 + NBKT;          // [196]
        if (tid < NBKT) { cnt1[tid] = 0; cnt2[tid] = 0; }
        __syncthreads();
        int e0 = bid * EDGES_PER_PASSC;
        for (int i = tid; i < EDGES_PER_PASSC; i += 256)
            atomicAdd(&cnt1[dst[e0 + i] >> 8], 1);
        __syncthreads();
        if (tid < NBKT) {
            int c = cnt1[tid];
            runbase[tid] = (c > 0) ? atomicAdd(&gcursor[tid], c) : 0;
        }
        __syncthreads();
        for (int i = tid; i < EDGES_PER_PASSC; i += 256) {
            int e = e0 + i;
            int d = dst[e];
            int b = d >> 8;
            int lr = atomicAdd(&cnt2[b], 1);
            int pos = b * BKT_CAP + runbase[b] + lr;
            edge_b[pos] = make_int2(src[e] | ((d & 255) << 16), __float_as_int(ew[e]));
        }
        return;
    }
    // ---- gemm path (v3) ----
    int gb = bid - NPASSC;                   // 0..3124
    int wv   = tid >> 6;                     // K-slice 0..3 (32 k's each)
    int lane = tid & 63;                     // output column
    int node0 = gb * 16;
    const float4* W4 = (const float4*)W1;
    float4* w1s4 = (float4*)w1s;
#pragma unroll
    for (int i = 0; i < 8; ++i) w1s4[tid + 256 * i] = W4[tid + 256 * i];
    __syncthreads();
    // pull this wave's W K-slice into registers (conflict-free: lanes span banks)
    int k0 = __builtin_amdgcn_readfirstlane(wv) * 32;   // force wave-uniform
    float Wreg[32];
#pragma unroll
    for (int kk = 0; kk < 32; ++kk) Wreg[kk] = w1s[(k0 + kk) * HID_DIM + lane];
    __syncthreads();                         // all waves done reading w1s
    float* psum = w1s;                       // overlay [4][16][64] = 16 KB
    const float* xbase = x + (long)node0 * IN_DIM + k0;  // wave-uniform pointer
#pragma unroll
    for (int n = 0; n < 16; n += 2) {
        const float4* xa4 = (const float4*)(xbase + (long)n * IN_DIM);
        const float4* xb4 = (const float4*)(xbase + (long)(n + 1) * IN_DIM);
        float accA = 0.f, accB = 0.f;
#pragma unroll
        for (int q = 0; q < 8; ++q) {
            float4 xa = xa4[q];              // uniform address -> scalar/broadcast load
            float4 xb = xb4[q];
            accA += xa.x * Wreg[4*q+0] + xa.y * Wreg[4*q+1] + xa.z * Wreg[4*q+2] + xa.w * Wreg[4*q+3];
            accB += xb.x * Wreg[4*q+0] + xb.y * Wreg[4*q+1] + xb.z * Wreg[4*q+2] + xb.w * Wreg[4*q+3];
        }
        psum[(wv * 16 + n) * 64 + lane]     = accA;
        psum[(wv * 16 + n + 1) * 64 + lane] = accB;
    }
    __syncthreads();
    // reduce 4 K-partials; thread (wv,lane) handles nodes wv*4..wv*4+3
#pragma unroll
    for (int i = 0; i < 4; ++i) {
        int n = wv * 4 + i;
        float s = psum[n * 64 + lane] + psum[(16 + n) * 64 + lane]
                + psum[(32 + n) * 64 + lane] + psum[(48 + n) * 64 + lane];
        h1b[(long)(node0 + n) * HID_DIM + lane] = __float2bfloat16(s);
    }
}

// =============== kernel 2: per-bucket fine sort + start/cnt/dinv ==============
// One block per bucket, 1024 threads: edge passes 4 strided iterations,
// 16 waves/CU for latency hiding. 256-wide scan guarded to tid<256.
__global__ __launch_bounds__(1024)
void bsort_kernel(const int* __restrict__ gcursor, const int2* __restrict__ edge_b,
                  int2* __restrict__ edge_s, int* __restrict__ start_g,
                  int* __restrict__ cnt_g, float* __restrict__ dinv) {
    __shared__ int   cnt[256];
    __shared__ int   cnt2[256];
    __shared__ float deg[256];
    __shared__ int   sc[256];
    int b   = blockIdx.x;
    int tid = threadIdx.x;
    int M    = gcursor[b];
    int base = b * BKT_CAP;
    if (tid < 256) { cnt[tid] = 0; cnt2[tid] = 0; deg[tid] = 0.0f; }
    __syncthreads();
    for (int i = tid; i < M; i += 1024) {
        int2 e = edge_b[base + i];
        int ld = (e.x >> 16) & 255;
        atomicAdd(&cnt[ld], 1);
        atomicAdd(&deg[ld], __int_as_float(e.y));
    }
    __syncthreads();
    // exclusive scan of cnt over 256 (Hillis-Steele inclusive, then shift)
    if (tid < 256) sc[tid] = cnt[tid];
    __syncthreads();
#pragma unroll
    for (int off = 1; off < 256; off <<= 1) {
        int t = (tid >= off && tid < 256) ? sc[tid - off] : 0;
        __syncthreads();
        if (tid < 256) sc[tid] += t;
        __syncthreads();
    }
    if (tid < 256) {
        int startL = sc[tid] - cnt[tid];     // exclusive
        int node = b * 256 + tid;
        if (node < N_NODES) {
            start_g[node] = base + startL;
            cnt_g[node]   = cnt[tid];
            dinv[node]    = rsqrtf(1.0f + deg[tid]);
        }
        sc[tid] = startL;                    // stash exclusive offsets for scatter
    }
    __syncthreads();
    for (int i = tid; i < M; i += 1024) {
        int2 e = edge_b[base + i];
        int ld = (e.x >> 16) & 255;
        int r = atomicAdd(&cnt2[ld], 1);
        edge_s[base + sc[ld] + r] = make_int2(e.x & 0xFFFF, e.y);
    }
}

// =============== kernel 3: gather L1 + finalize + relu + W2 GEMV ==============
// Wave per node. Lane l owns column pair {2(l&31), 2(l&31)+1}; lanes 0-31
// process even edges, lanes 32-63 odd edges -> one 4B-lane load covers TWO
// h1b rows per instruction (halves VMEM inst count). bf16->f32 via bit shift.
__global__ void gather1_layer2_kernel(const int* __restrict__ start_g, const int* __restrict__ cnt_g,
                                      const int2* __restrict__ edge_s,
                                      const __hip_bfloat16* __restrict__ h1b,
                                      const float* __restrict__ dinv, const float* __restrict__ b1,
                                      const float* __restrict__ W2, float* __restrict__ h2s) {
    __shared__ int2 meta[4][64];
    int wave = (blockIdx.x * blockDim.x + threadIdx.x) >> 6;
    int wl = threadIdx.x >> 6;
    int lane = threadIdx.x & 63;
    if (wave >= N_NODES) return;
    int s0 = start_g[wave];
    int ctotal = cnt_g[wave];
    int c0 = (lane & 31) * 2;                // column pair this lane owns
    int half = lane >> 5;                    // 0: even edges, 1: odd edges
    float accA = 0.f, accB = 0.f;            // col c0 / c0+1
    float accA2 = 0.f, accB2 = 0.f;          // second pair for ILP
    for (int done = 0; done < ctotal; done += 64) {
        int cnt = ctotal - done;
        if (cnt > 64) cnt = 64;
        if (lane < cnt) {
            int2 m = edge_s[s0 + done + lane];
            float w = __int_as_float(m.y) * dinv[m.x];   // fold dinv[src]
            meta[wl][lane] = make_int2(m.x, __float_as_int(w));
        }
        __builtin_amdgcn_wave_barrier();
        int cnte = cnt & ~1;
        int j = 0;
        for (; j + 16 <= cnte; j += 16) {    // 16 edges = 8 paired loads in flight
            int2 m0 = meta[wl][j +  0 + half];
            int2 m1 = meta[wl][j +  2 + half];
            int2 m2 = meta[wl][j +  4 + half];
            int2 m3 = meta[wl][j +  6 + half];
            int2 m4 = meta[wl][j +  8 + half];
            int2 m5 = meta[wl][j + 10 + half];
            int2 m6 = meta[wl][j + 12 + half];
            int2 m7 = meta[wl][j + 14 + half];
            unsigned int p0 = *(const unsigned int*)&h1b[m0.x * HID_DIM + c0];
            unsigned int p1 = *(const unsigned int*)&h1b[m1.x * HID_DIM + c0];
            unsigned int p2 = *(const unsigned int*)&h1b[m2.x * HID_DIM + c0];
            unsigned int p3 = *(const unsigned int*)&h1b[m3.x * HID_DIM + c0];
            unsigned int p4 = *(const unsigned int*)&h1b[m4.x * HID_DIM + c0];
            unsigned int p5 = *(const unsigned int*)&h1b[m5.x * HID_DIM + c0];
            unsigned int p6 = *(const unsigned int*)&h1b[m6.x * HID_DIM + c0];
            unsigned int p7 = *(const unsigned int*)&h1b[m7.x * HID_DIM + c0];
            float w0 = __int_as_float(m0.y), w1 = __int_as_float(m1.y);
            float w2 = __int_as_float(m2.y), w3 = __int_as_float(m3.y);
            float w4 = __int_as_float(m4.y), w5 = __int_as_float(m5.y);
            float w6 = __int_as_float(m6.y), w7 = __int_as_float(m7.y);
            accA  += w0 * __uint_as_float(p0 << 16);
            accB  += w0 * __uint_as_float(p0 & 0xFFFF0000u);
            accA2 += w1 * __uint_as_float(p1 << 16);
            accB2 += w1 * __uint_as_float(p1 & 0xFFFF0000u);
            accA  += w2 * __uint_as_float(p2 << 16);
            accB  += w2 * __uint_as_float(p2 & 0xFFFF0000u);
            accA2 += w3 * __uint_as_float(p3 << 16);
            accB2 += w3 * __uint_as_float(p3 & 0xFFFF0000u);
            accA  += w4 * __uint_as_float(p4 << 16);
            accB  += w4 * __uint_as_float(p4 & 0xFFFF0000u);
            accA2 += w5 * __uint_as_float(p5 << 16);
            accB2 += w5 * __uint_as_float(p5 & 0xFFFF0000u);
            accA  += w6 * __uint_as_float(p6 << 16);
            accB  += w6 * __uint_as_float(p6 & 0xFFFF0000u);
            accA2 += w7 * __uint_as_float(p7 << 16);
            accB2 += w7 * __uint_as_float(p7 & 0xFFFF0000u);
        }
        for (; j + 2 <= cnte; j += 2) {
            int2 m = meta[wl][j + half];
            unsigned int p = *(const unsigned int*)&h1b[m.x * HID_DIM + c0];
            accA += __int_as_float(m.y) * __uint_as_float(p << 16);
            accB += __int_as_float(m.y) * __uint_as_float(p & 0xFFFF0000u);
        }
        if (cnt & 1) {                       // odd tail: process in half 0 only
            if (half == 0) {
                int2 m = meta[wl][cnt - 1];
                unsigned int p = *(const unsigned int*)&h1b[m.x * HID_DIM + c0];
                accA += __int_as_float(m.y) * __uint_as_float(p << 16);
                accB += __int_as_float(m.y) * __uint_as_float(p & 0xFFFF0000u);
            }
        }
        __builtin_amdgcn_wave_barrier();
    }
    accA += accA2; accB += accB2;
    accA += __shfl_xor(accA, 32, 64);        // merge even/odd halves
    accB += __shfl_xor(accB, 32, 64);
    float di = dinv[wave];
    unsigned int sp = *(const unsigned int*)&h1b[wave * HID_DIM + c0];
    float s0f = __uint_as_float(sp << 16);
    float s1f = __uint_as_float(sp & 0xFFFF0000u);
    float z0 = di * (accA + di * s0f) + b1[c0];
    float z1 = di * (accB + di * s1f) + b1[c0 + 1];
    float h0 = fmaxf(z0, 0.0f);
    float h1v = fmaxf(z1, 0.0f);
    float v = h0 * W2[c0] + h1v * W2[c0 + 1];
#pragma unroll
    for (int off = 16; off > 0; off >>= 1)
        v += __shfl_down(v, off, 32);
    if (lane == 0) h2s[wave] = v * di;
}

// =============== kernel 4: gather L2 + sigmoid ================================
// 16 lanes per node (4 nodes/wave): mean degree 16 -> ~1 lane-parallel
// iteration; node runs are adjacent in the bucket so edge_s reads are nearly
// contiguous per wave.
__global__ void gather2_final_kernel(const int* __restrict__ start_g, const int* __restrict__ cnt_g,
                                     const int2* __restrict__ edge_s,
                                     const float* __restrict__ h2s, const float* __restrict__ dinv,
                                     const float* __restrict__ b2, float* __restrict__ out) {
    int t = blockIdx.x * blockDim.x + threadIdx.x;
    int n = t >> 4;
    int sub = t & 15;
    if (n >= N_NODES) return;
    int s0 = start_g[n];
    int cnt = cnt_g[n];
    float acc = 0.0f;
    for (int j = sub; j < cnt; j += 16) {
        int2 m = edge_s[s0 + j];
        acc += __int_as_float(m.y) * h2s[m.x];   // h2s already has dinv[src] folded
    }
#pragma unroll
    for (int off = 8; off > 0; off >>= 1)
        acc += __shfl_down(acc, off, 16);
    if (sub == 0) {
        float z = dinv[n] * (acc + h2s[n]) + b2[0];
        out[n] = 1.0f / (1.0f + expf(-z));
    }
}

extern "C" void kernel_launch(void* const* d_in, const int* in_sizes, int n_in,
                              void* d_out, int out_size, void* d_ws, size_t ws_size,
                              hipStream_t stream) {
    const float* x  = (const float*)d_in[0];
    const int*   ei = (const int*)d_in[1];
    const float* ew = (const float*)d_in[2];
    const float* W1 = (const float*)d_in[3];
    const float* b1 = (const float*)d_in[4];
    const float* W2 = (const float*)d_in[5];
    const float* b2 = (const float*)d_in[6];
    float* out = (float*)d_out;

    const int* src = ei;
    const int* dst = ei + N_EDGES;

    // workspace layout (int2 arrays first for 8B alignment)
    char* ws = (char*)d_ws;
    int2*  edge_b  = (int2*)ws;              ws += (size_t)NBKT * BKT_CAP * sizeof(int2);
    int2*  edge_s  = (int2*)ws;              ws += (size_t)NBKT * BKT_CAP * sizeof(int2);
    int*   gcursor = (int*)ws;               ws += NBKT * sizeof(int);
    int*   start_g = (int*)ws;               ws += N_NODES * sizeof(int);
    int*   cnt_g   = (int*)ws;               ws += N_NODES * sizeof(int);
    float* dinv    = (float*)ws;             ws += N_NODES * sizeof(float);
    float* h2s     = (float*)ws;             ws += N_NODES * sizeof(float);
    // align h1b to 128 B so each 64xbf16 row sits in a single cache line
    ws = (char*)(((uintptr_t)ws + 127) & ~(uintptr_t)127);
    __hip_bfloat16* h1b = (__hip_bfloat16*)ws;  // N_NODES * HID_DIM bf16

    hipMemsetAsync(gcursor, 0, NBKT * sizeof(int), stream);
    partgemm_kernel<<<NPASSC + NGEMM, 256, 0, stream>>>(src, dst, ew, gcursor, edge_b, x, W1, h1b);
    bsort_kernel<<<NBKT, 1024, 0, stream>>>(gcursor, edge_b, edge_s, start_g, cnt_g, dinv);
    gather1_layer2_kernel<<<(N_NODES * 64) / 256, 256, 0, stream>>>(start_g, cnt_g, edge_s, h1b, dinv, b1, W2, h2s);
    gather2_final_kernel<<<(N_NODES * 16 + 255) / 256, 256, 0, stream>>>(start_g, cnt_g, edge_s, h2s, dinv, b2, out);
}

// Round 5
// 155.063 us; speedup vs baseline: 1.0527x; 1.0527x over previous
//
#include <hip/hip_runtime.h>
#include <hip/hip_bf16.h>
#include <math.h>

#define N_NODES 50000
#define N_EDGES 800000
#define IN_DIM  128
#define HID_DIM 64

#define NBKT     196        // buckets of 256 nodes: bucket = node >> 8
#define BKT_CAP  5000       // mean 4092, sd 64 -> +14 sigma, safe
#define NPASSC   200        // partition blocks, 4000 edges each
#define EDGES_PER_PASSC (N_EDGES / NPASSC)   // 4000
#define GEMM_NODES 64       // nodes per gemm block
#define NGEMM    782        // ceil(50000 / 64)
#define XS_LD    132        // xs row pad: bank stride 4, 2-way aliasing (free)

// =============== kernel 1: fused bucket-partition (blocks 0..199) =============
// =============== + gemm h1b = bf16(x @ W1) (blocks 200..981) ==================
// gemm v4: register-tiled LDS GEMM. Lane owns 4 nodes x 4 cols; per 4-k step
// 8 ds_read_b128 feed 64 FMA wave-instrs. xs padded to 132 (2-way bank alias,
// free); W reads broadcast. No psum round-trip; each lane writes its tile.
__global__ __launch_bounds__(256)
void partgemm_kernel(const int* __restrict__ src, const int* __restrict__ dst,
                     const float* __restrict__ ew, int* __restrict__ gcursor,
                     int2* __restrict__ edge_b,
                     const float* __restrict__ x, const float* __restrict__ W1,
                     __hip_bfloat16* __restrict__ h1b) {
    __shared__ float w1s[IN_DIM * HID_DIM];     // 32 KB (PassC overlays counters)
    __shared__ float xs[GEMM_NODES][XS_LD];     // 33.8 KB
    int bid = blockIdx.x;
    int tid = threadIdx.x;
    if (bid < NPASSC) {
        // ---- PassC: partition into buckets ----
        int* cnt1    = (int*)w1s;            // [196]
        int* cnt2    = cnt1 + NBKT;          // [196]
        int* runbase = cnt2 + NBKT;          // [196]
        if (tid < NBKT) { cnt1[tid] = 0; cnt2[tid] = 0; }
        __syncthreads();
        int e0 = bid * EDGES_PER_PASSC;
        for (int i = tid; i < EDGES_PER_PASSC; i += 256)
            atomicAdd(&cnt1[dst[e0 + i] >> 8], 1);
        __syncthreads();
        if (tid < NBKT) {
            int c = cnt1[tid];
            runbase[tid] = (c > 0) ? atomicAdd(&gcursor[tid], c) : 0;
        }
        __syncthreads();
        for (int i = tid; i < EDGES_PER_PASSC; i += 256) {
            int e = e0 + i;
            int d = dst[e];
            int b = d >> 8;
            int lr = atomicAdd(&cnt2[b], 1);
            int pos = b * BKT_CAP + runbase[b] + lr;
            edge_b[pos] = make_int2(src[e] | ((d & 255) << 16), __float_as_int(ew[e]));
        }
        return;
    }
    // ---- gemm path (v4: register tiling) ----
    int gb = bid - NPASSC;                   // 0..781
    int node0 = gb * GEMM_NODES;
    // stage W (coalesced, 8 float4/thread)
    const float4* W4 = (const float4*)W1;
    float4* w1s4 = (float4*)w1s;
#pragma unroll
    for (int i = 0; i < 8; ++i) w1s4[tid + 256 * i] = W4[tid + 256 * i];
    // stage x: thread (r=tid>>2, q=tid&3) loads row-quarter, clamped
    {
        int r = tid >> 2, q = tid & 3;
        int row = node0 + r;
        if (row >= N_NODES) row = N_NODES - 1;
        const float4* xr = (const float4*)(x + (long)row * IN_DIM + q * 32);
#pragma unroll
        for (int i = 0; i < 8; ++i)
            *(float4*)&xs[r][q * 32 + i * 4] = xr[i];
    }
    __syncthreads();
    int w    = tid >> 6;                     // wave: col block w*16
    int lane = tid & 63;
    int ng   = lane >> 2;                    // 16 node-groups (stride 16 rows)
    int jg   = lane & 3;                     // 4 col-groups
    int j0   = w * 16 + jg * 4;
    float acc[4][4] = {{0.f}};
#pragma unroll 2
    for (int k = 0; k < IN_DIM; k += 4) {
        float4 wr0 = *(const float4*)&w1s[(k + 0) * HID_DIM + j0];
        float4 wr1 = *(const float4*)&w1s[(k + 1) * HID_DIM + j0];
        float4 wr2 = *(const float4*)&w1s[(k + 2) * HID_DIM + j0];
        float4 wr3 = *(const float4*)&w1s[(k + 3) * HID_DIM + j0];
#pragma unroll
        for (int i = 0; i < 4; ++i) {
            float4 xv = *(const float4*)&xs[ng + 16 * i][k];
            acc[i][0] += xv.x * wr0.x + xv.y * wr1.x + xv.z * wr2.x + xv.w * wr3.x;
            acc[i][1] += xv.x * wr0.y + xv.y * wr1.y + xv.z * wr2.y + xv.w * wr3.y;
            acc[i][2] += xv.x * wr0.z + xv.y * wr1.z + xv.z * wr2.z + xv.w * wr3.z;
            acc[i][3] += xv.x * wr0.w + xv.y * wr1.w + xv.z * wr2.w + xv.w * wr3.w;
        }
    }
#pragma unroll
    for (int i = 0; i < 4; ++i) {
        int n = node0 + ng + 16 * i;
        if (n < N_NODES) {
            __hip_bfloat16 bf[4];
            bf[0] = __float2bfloat16(acc[i][0]);
            bf[1] = __float2bfloat16(acc[i][1]);
            bf[2] = __float2bfloat16(acc[i][2]);
            bf[3] = __float2bfloat16(acc[i][3]);
            *(uint2*)&h1b[(long)n * HID_DIM + j0] = *(uint2*)bf;   // 8B store
        }
    }
}

// =============== kernel 2: per-bucket fine sort + start/cnt/dinv ==============
__global__ __launch_bounds__(1024)
void bsort_kernel(const int* __restrict__ gcursor, const int2* __restrict__ edge_b,
                  int2* __restrict__ edge_s, int* __restrict__ start_g,
                  int* __restrict__ cnt_g, float* __restrict__ dinv) {
    __shared__ int   cnt[256];
    __shared__ int   cnt2[256];
    __shared__ float deg[256];
    __shared__ int   sc[256];
    int b   = blockIdx.x;
    int tid = threadIdx.x;
    int M    = gcursor[b];
    int base = b * BKT_CAP;
    if (tid < 256) { cnt[tid] = 0; cnt2[tid] = 0; deg[tid] = 0.0f; }
    __syncthreads();
    for (int i = tid; i < M; i += 1024) {
        int2 e = edge_b[base + i];
        int ld = (e.x >> 16) & 255;
        atomicAdd(&cnt[ld], 1);
        atomicAdd(&deg[ld], __int_as_float(e.y));
    }
    __syncthreads();
    if (tid < 256) sc[tid] = cnt[tid];
    __syncthreads();
#pragma unroll
    for (int off = 1; off < 256; off <<= 1) {
        int t = (tid >= off && tid < 256) ? sc[tid - off] : 0;
        __syncthreads();
        if (tid < 256) sc[tid] += t;
        __syncthreads();
    }
    if (tid < 256) {
        int startL = sc[tid] - cnt[tid];     // exclusive
        int node = b * 256 + tid;
        if (node < N_NODES) {
            start_g[node] = base + startL;
            cnt_g[node]   = cnt[tid];
            dinv[node]    = rsqrtf(1.0f + deg[tid]);
        }
        sc[tid] = startL;                    // stash exclusive offsets for scatter
    }
    __syncthreads();
    for (int i = tid; i < M; i += 1024) {
        int2 e = edge_b[base + i];
        int ld = (e.x >> 16) & 255;
        int r = atomicAdd(&cnt2[ld], 1);
        edge_s[base + sc[ld] + r] = make_int2(e.x & 0xFFFF, e.y);
    }
}

// =============== kernel 3: gather L1 + finalize + relu + W2 GEMV ==============
// Wave per node. Lane l owns column pair {2(l&31), 2(l&31)+1}; lanes 0-31
// process even edges, lanes 32-63 odd edges -> one 4B-lane load covers TWO
// h1b rows per instruction. bf16->f32 via bit shift.
__global__ void gather1_layer2_kernel(const int* __restrict__ start_g, const int* __restrict__ cnt_g,
                                      const int2* __restrict__ edge_s,
                                      const __hip_bfloat16* __restrict__ h1b,
                                      const float* __restrict__ dinv, const float* __restrict__ b1,
                                      const float* __restrict__ W2, float* __restrict__ h2s) {
    __shared__ int2 meta[4][64];
    int wave = (blockIdx.x * blockDim.x + threadIdx.x) >> 6;
    int wl = threadIdx.x >> 6;
    int lane = threadIdx.x & 63;
    if (wave >= N_NODES) return;
    int s0 = start_g[wave];
    int ctotal = cnt_g[wave];
    int c0 = (lane & 31) * 2;                // column pair this lane owns
    int half = lane >> 5;                    // 0: even edges, 1: odd edges
    float accA = 0.f, accB = 0.f;
    float accA2 = 0.f, accB2 = 0.f;
    for (int done = 0; done < ctotal; done += 64) {
        int cnt = ctotal - done;
        if (cnt > 64) cnt = 64;
        if (lane < cnt) {
            int2 m = edge_s[s0 + done + lane];
            float w = __int_as_float(m.y) * dinv[m.x];   // fold dinv[src]
            meta[wl][lane] = make_int2(m.x, __float_as_int(w));
        }
        __builtin_amdgcn_wave_barrier();
        int cnte = cnt & ~1;
        int j = 0;
        for (; j + 16 <= cnte; j += 16) {
            int2 m0 = meta[wl][j +  0 + half];
            int2 m1 = meta[wl][j +  2 + half];
            int2 m2 = meta[wl][j +  4 + half];
            int2 m3 = meta[wl][j +  6 + half];
            int2 m4 = meta[wl][j +  8 + half];
            int2 m5 = meta[wl][j + 10 + half];
            int2 m6 = meta[wl][j + 12 + half];
            int2 m7 = meta[wl][j + 14 + half];
            unsigned int p0 = *(const unsigned int*)&h1b[m0.x * HID_DIM + c0];
            unsigned int p1 = *(const unsigned int*)&h1b[m1.x * HID_DIM + c0];
            unsigned int p2 = *(const unsigned int*)&h1b[m2.x * HID_DIM + c0];
            unsigned int p3 = *(const unsigned int*)&h1b[m3.x * HID_DIM + c0];
            unsigned int p4 = *(const unsigned int*)&h1b[m4.x * HID_DIM + c0];
            unsigned int p5 = *(const unsigned int*)&h1b[m5.x * HID_DIM + c0];
            unsigned int p6 = *(const unsigned int*)&h1b[m6.x * HID_DIM + c0];
            unsigned int p7 = *(const unsigned int*)&h1b[m7.x * HID_DIM + c0];
            float w0 = __int_as_float(m0.y), w1 = __int_as_float(m1.y);
            float w2 = __int_as_float(m2.y), w3 = __int_as_float(m3.y);
            float w4 = __int_as_float(m4.y), w5 = __int_as_float(m5.y);
            float w6 = __int_as_float(m6.y), w7 = __int_as_float(m7.y);
            accA  += w0 * __uint_as_float(p0 << 16);
            accB  += w0 * __uint_as_float(p0 & 0xFFFF0000u);
            accA2 += w1 * __uint_as_float(p1 << 16);
            accB2 += w1 * __uint_as_float(p1 & 0xFFFF0000u);
            accA  += w2 * __uint_as_float(p2 << 16);
            accB  += w2 * __uint_as_float(p2 & 0xFFFF0000u);
            accA2 += w3 * __uint_as_float(p3 << 16);
            accB2 += w3 * __uint_as_float(p3 & 0xFFFF0000u);
            accA  += w4 * __uint_as_float(p4 << 16);
            accB  += w4 * __uint_as_float(p4 & 0xFFFF0000u);
            accA2 += w5 * __uint_as_float(p5 << 16);
            accB2 += w5 * __uint_as_float(p5 & 0xFFFF0000u);
            accA  += w6 * __uint_as_float(p6 << 16);
            accB  += w6 * __uint_as_float(p6 & 0xFFFF0000u);
            accA2 += w7 * __uint_as_float(p7 << 16);
            accB2 += w7 * __uint_as_float(p7 & 0xFFFF0000u);
        }
        for (; j + 2 <= cnte; j += 2) {
            int2 m = meta[wl][j + half];
            unsigned int p = *(const unsigned int*)&h1b[m.x * HID_DIM + c0];
            accA += __int_as_float(m.y) * __uint_as_float(p << 16);
            accB += __int_as_float(m.y) * __uint_as_float(p & 0xFFFF0000u);
        }
        if (cnt & 1) {
            if (half == 0) {
                int2 m = meta[wl][cnt - 1];
                unsigned int p = *(const unsigned int*)&h1b[m.x * HID_DIM + c0];
                accA += __int_as_float(m.y) * __uint_as_float(p << 16);
                accB += __int_as_float(m.y) * __uint_as_float(p & 0xFFFF0000u);
            }
        }
        __builtin_amdgcn_wave_barrier();
    }
    accA += accA2; accB += accB2;
    accA += __shfl_xor(accA, 32, 64);        // merge even/odd halves
    accB += __shfl_xor(accB, 32, 64);
    float di = dinv[wave];
    unsigned int sp = *(const unsigned int*)&h1b[wave * HID_DIM + c0];
    float s0f = __uint_as_float(sp << 16);
    float s1f = __uint_as_float(sp & 0xFFFF0000u);
    float z0 = di * (accA + di * s0f) + b1[c0];
    float z1 = di * (accB + di * s1f) + b1[c0 + 1];
    float h0 = fmaxf(z0, 0.0f);
    float h1v = fmaxf(z1, 0.0f);
    float v = h0 * W2[c0] + h1v * W2[c0 + 1];
#pragma unroll
    for (int off = 16; off > 0; off >>= 1)
        v += __shfl_down(v, off, 32);
    if (lane == 0) h2s[wave] = v * di;
}

// =============== kernel 4: gather L2 + sigmoid ================================
__global__ void gather2_final_kernel(const int* __restrict__ start_g, const int* __restrict__ cnt_g,
                                     const int2* __restrict__ edge_s,
                                     const float* __restrict__ h2s, const float* __restrict__ dinv,
                                     const float* __restrict__ b2, float* __restrict__ out) {
    int t = blockIdx.x * blockDim.x + threadIdx.x;
    int n = t >> 4;
    int sub = t & 15;
    if (n >= N_NODES) return;
    int s0 = start_g[n];
    int cnt = cnt_g[n];
    float acc = 0.0f;
    for (int j = sub; j < cnt; j += 16) {
        int2 m = edge_s[s0 + j];
        acc += __int_as_float(m.y) * h2s[m.x];   // h2s already has dinv[src] folded
    }
#pragma unroll
    for (int off = 8; off > 0; off >>= 1)
        acc += __shfl_down(acc, off, 16);
    if (sub == 0) {
        float z = dinv[n] * (acc + h2s[n]) + b2[0];
        out[n] = 1.0f / (1.0f + expf(-z));
    }
}

extern "C" void kernel_launch(void* const* d_in, const int* in_sizes, int n_in,
                              void* d_out, int out_size, void* d_ws, size_t ws_size,
                              hipStream_t stream) {
    const float* x  = (const float*)d_in[0];
    const int*   ei = (const int*)d_in[1];
    const float* ew = (const float*)d_in[2];
    const float* W1 = (const float*)d_in[3];
    const float* b1 = (const float*)d_in[4];
    const float* W2 = (const float*)d_in[5];
    const float* b2 = (const float*)d_in[6];
    float* out = (float*)d_out;

    const int* src = ei;
    const int* dst = ei + N_EDGES;

    // workspace layout (int2 arrays first for 8B alignment)
    char* ws = (char*)d_ws;
    int2*  edge_b  = (int2*)ws;              ws += (size_t)NBKT * BKT_CAP * sizeof(int2);
    int2*  edge_s  = (int2*)ws;              ws += (size_t)NBKT * BKT_CAP * sizeof(int2);
    int*   gcursor = (int*)ws;               ws += NBKT * sizeof(int);
    int*   start_g = (int*)ws;               ws += N_NODES * sizeof(int);
    int*   cnt_g   = (int*)ws;               ws += N_NODES * sizeof(int);
    float* dinv    = (float*)ws;             ws += N_NODES * sizeof(float);
    float* h2s     = (float*)ws;             ws += N_NODES * sizeof(float);
    // align h1b to 128 B so each 64xbf16 row sits in a single cache line
    ws = (char*)(((uintptr_t)ws + 127) & ~(uintptr_t)127);
    __hip_bfloat16* h1b = (__hip_bfloat16*)ws;  // N_NODES * HID_DIM bf16

    hipMemsetAsync(gcursor, 0, NBKT * sizeof(int), stream);
    partgemm_kernel<<<NPASSC + NGEMM, 256, 0, stream>>>(src, dst, ew, gcursor, edge_b, x, W1, h1b);
    bsort_kernel<<<NBKT, 1024, 0, stream>>>(gcursor, edge_b, edge_s, start_g, cnt_g, dinv);
    gather1_layer2_kernel<<<(N_NODES * 64) / 256, 256, 0, stream>>>(start_g, cnt_g, edge_s, h1b, dinv, b1, W2, h2s);
    gather2_final_kernel<<<(N_NODES * 16 + 255) / 256, 256, 0, stream>>>(start_g, cnt_g, edge_s, h2s, dinv, b2, out);
}